// Round 20
// baseline (304.488 us; speedup 1.0000x reference)
//
#include <hip/hip_runtime.h>
#include <math.h>

typedef __bf16 bf8_t __attribute__((ext_vector_type(8)));
typedef short  s8_t  __attribute__((ext_vector_type(8)));
typedef float  f4_t  __attribute__((ext_vector_type(4)));
typedef float  f16v  __attribute__((ext_vector_type(16)));

#define CIN   128
#define COUT  128
#define RES   256
#define WDIM  512
#define PROWS 258   // padded rows: -1 .. 256
#define PCOLS 264   // padded cols: -4 .. 259
#define PSTR  135   // LDS plane stride in 16B groups
#define BGRP  (8 * PSTR)   // 1080 groups per half-row buffer

// round-to-nearest-even f32 -> bf16 bits (inputs finite, no NaN handling)
static __device__ __forceinline__ unsigned short f2bf(float f) {
    unsigned u = __float_as_uint(f);
    unsigned r = (u + 0x7fffu + ((u >> 16) & 1u)) >> 16;
    return (unsigned short)r;
}

// ---- prep 1: styles[b][i] = (w[b]·affine_w[i])/sqrt(512) + affine_b[i] ----
__global__ void k_styles(const float* __restrict__ w, const float* __restrict__ aw,
                         const float* __restrict__ ab, float* __restrict__ styles) {
    int t = blockIdx.x * 256 + threadIdx.x;      // 1024 threads: (b, i)
    int b = t >> 7, i = t & 127;
    const float4* wr = (const float4*)(w + b * WDIM);
    const float4* ar = (const float4*)(aw + i * WDIM);
    float s = 0.f;
    for (int j = 0; j < WDIM / 4; ++j) {
        float4 a = ar[j], c = wr[j];
        s += a.x * c.x + a.y * c.y + a.z * c.z + a.w * c.w;
    }
    styles[t] = s * 0.04419417382415922f + ab[i];   // 1/sqrt(512)
}

// ---- prep 2: w2[o][i] = sum_k weight^2 ;
//      wb3[((kk*8+ks16)*128+o)*16 + i15] = bf16(weight[o][ks16*16+i15][kk])
//      (32x32x16-MFMA A layout: lane l reads 16B at co=l&31, khalf=l>>5;
//       one fragment = contiguous 1KB) ----
__global__ void k_wprep(const float* __restrict__ wt, float* __restrict__ w2,
                        unsigned short* __restrict__ wb3) {
    int t = blockIdx.x * 256 + threadIdx.x;      // 16384 threads: (o, i)
    int o = t >> 7, i = t & 127;
    int ks16 = i >> 4, i15 = i & 15;
    float s = 0.f;
    for (int kk = 0; kk < 9; ++kk) {
        float v = wt[(o * CIN + i) * 9 + kk];
        s += v * v;
        wb3[((kk * 8 + ks16) * COUT + o) * 16 + i15] = f2bf(v);
    }
    w2[o * CIN + i] = s;
}

// ---- prep 3: dcoef[b][o] = 1/sqrt(sum_i w2[o][i]*styles[b][i]^2 + 1e-8) ----
__global__ void k_dcoef(const float* __restrict__ w2, const float* __restrict__ styles,
                        float* __restrict__ dcoef) {
    int t = blockIdx.x * 256 + threadIdx.x;      // 1024 threads: (b, o)
    int b = t >> 7, o = t & 127;
    float s = 0.f;
    for (int i = 0; i < CIN; ++i) {
        float st = styles[b * CIN + i];
        s += w2[o * CIN + i] * st * st;
    }
    dcoef[t] = 1.0f / sqrtf(s + 1e-8f);
}

// ---- prep 4: modulated bf16 x in MFMA-native padded layout ----
// xb flat group index t = ((b*16+cig)*PROWS + pr)*PCOLS + pc ; group = 8 ch = 16B
// pr = row+1 (rows -1..256), pc = col+4 (cols -4..259); pads are zero.
__global__ __launch_bounds__(256) void k_prep_x(
    const float* __restrict__ x, const float* __restrict__ styles,
    unsigned short* __restrict__ xb) {
    int t = blockIdx.x * 256 + threadIdx.x;      // 8*16*258*264 = 8,718,336 groups
    int pc = t % PCOLS;
    int r1 = t / PCOLS;
    int pr = r1 % PROWS;
    int bc = r1 / PROWS;                         // b*16 + cig
    int b = bc >> 4, cig = bc & 15;
    int r = pr - 1, c = pc - 4;
    unsigned short v[8];
    if ((r >= 0) & (r < RES) & (c >= 0) & (c < RES)) {
        const float* xp = x + (((size_t)b * CIN + cig * 8) * RES + r) * RES + c;
        const float* st = styles + b * CIN + cig * 8;
        #pragma unroll
        for (int j = 0; j < 8; ++j)
            v[j] = f2bf(__builtin_nontemporal_load(xp + (size_t)j * RES * RES) * st[j]);
    } else {
        #pragma unroll
        for (int j = 0; j < 8; ++j) v[j] = 0;
    }
    *(s8_t*)(xb + (size_t)t * 8) = *(const s8_t*)v;   // 16B/lane, wave-contiguous
}

// ---- main: R20 = R17 geometry (2 rows x 128 co x 128 px, 8 waves, 8 phases,
//      2-slot gload_lds ring) with 32x32x16 MFMA tiles: wave = (co-half ch,
//      px-half ph, row ri), acc[2][2] x f32x16 = 64 AGPR. Per phase per wave:
//      24 A + 24 B loads + 48 MFMA (vs R17's 12+48+96) -- DS reads HALVED,
//      MFMAs 2x longer (better latency cover per issue slot).
//      R6 scattered epilogue; 32x32 C/D: col=lane&31, row=(reg&3)+8(reg>>2)+4hi. ----
__global__ __launch_bounds__(512, 4) void k_conv19(
    const float* __restrict__ noise, const float* __restrict__ nstrp,
    const float* __restrict__ bias, const float* __restrict__ dcoef,
    const unsigned short* __restrict__ wb3, const unsigned short* __restrict__ xb,
    float* __restrict__ out) {

    __shared__ s8_t xs[2][BGRP];                 // 2 x 17280 B ring
    __shared__ float s_dc[COUT], s_bias[COUT];   // 1 KB  (total 35.6 KB)

    int blk0 = blockIdx.x;
    int blk  = (blk0 & 7) * 256 + (blk0 >> 3);   // XCD swizzle (2048 blocks, bijective)
    int b   = blk >> 8;
    int rem = blk & 255;
    int y0  = (rem >> 1) << 1;                   // first output row (even)
    int w0  = (rem & 1) << 7;

    int tid = threadIdx.x;
    int lane = tid & 63, wave = tid >> 6;        // 8 waves
    int ch = wave & 1;                           // co-half (64 co)
    int ph = (wave >> 1) & 1;                    // px-half (64 px)
    int ri = wave >> 2;                          // output-row offset 0/1
    int l31 = lane & 31, hi = lane >> 5;

    const unsigned short* xbb = xb + (size_t)b * ((size_t)16 * PROWS * PCOLS * 8);
    // per-lane A base for 32x32x16: co = ch*64 + mt*32 + l31, khalf = hi
    const unsigned short* awp3 = wb3 + (ch * 64 + l31) * 16 + hi * 8;
    int pbase = ph * 64;

    // stage phase p (padded row pr = y0 + p/2, ci-half = p&1) into ring slot:
    // 1080 groups, linear LDS dest, 17 wave-loads spread over 8 waves
    auto stage = [&](int slot, int p) {
        int pr = y0 + (p >> 1);
        int cb = (p & 1) * 8;
        #pragma unroll
        for (int li = 0; li < 3; ++li) {
            int l = wave + li * 8;               // l in 0..16
            if (l < 17) {
                int g = l * 64 + lane;
                if (g < BGRP) {
                    int cig = (int)(((unsigned)g * 31069u) >> 22);   // g / 135
                    int col = g - cig * PSTR;
                    int cs = col > 131 ? 131 : col;  // pad groups: dup col 131
                    const unsigned short* src = xbb
                        + (((size_t)(cb + cig) * PROWS + pr) * PCOLS + (w0 + 2 + cs)) * 8;
                    __builtin_amdgcn_global_load_lds(
                        (const __attribute__((address_space(1))) unsigned int*)src,
                        (__attribute__((address_space(3))) unsigned int*)&xs[slot][g],
                        16, 0, 0);
                }
            }
        }
    };

    f16v acc[2][2];                              // [mt][nt] 32x32 tiles = 64 AGPR
    #pragma unroll
    for (int m = 0; m < 2; ++m)
        #pragma unroll
        for (int n = 0; n < 2; ++n)
            acc[m][n] = (f16v)0.f;

    // prologue: fill both slots, then small table loads
    stage(0, 0);
    stage(1, 1);
    if (tid < 128)      s_dc[tid] = dcoef[b * COUT + tid];
    else if (tid < 256) s_bias[tid - 128] = bias[tid - 128];
    __syncthreads();                             // drains all prologue loads

    // 8 phases: row = p>>1 (pr = y0+row), half = p&1. Wave computes kh = row - ri.
    #pragma unroll
    for (int p = 0; p < 8; ++p) {
        int buf = p & 1;
        int row = p >> 1, half = p & 1;
        int kh = row - ri;
        if (kh >= 0 && kh <= 2) {                // wave-uniform branch
            #pragma unroll
            for (int kw = 0; kw < 3; ++kw) {
                int kk = kh * 3 + kw;
                #pragma unroll
                for (int k16 = 0; k16 < 4; ++k16) {   // 16-ci slices of this half
                    int ks16 = half * 4 + k16;
                    const unsigned short* ak = awp3 + (kk * 8 + ks16) * COUT * 16;
                    s8_t af[2], bfg[2];
                    #pragma unroll
                    for (int mt = 0; mt < 2; ++mt)
                        af[mt] = *(const s8_t*)(ak + mt * 32 * 16);  // contiguous 1KB
                    #pragma unroll
                    for (int nt = 0; nt < 2; ++nt)
                        bfg[nt] = xs[buf][(2 * k16 + hi) * PSTR
                                          + pbase + nt * 32 + l31 + kw + 1];
                    __builtin_amdgcn_s_setprio(1);
                    #pragma unroll
                    for (int mt = 0; mt < 2; ++mt)
                        #pragma unroll
                        for (int nt = 0; nt < 2; ++nt)
                            acc[mt][nt] = __builtin_amdgcn_mfma_f32_32x32x16_bf16(
                                __builtin_bit_cast(bf8_t, af[mt]),
                                __builtin_bit_cast(bf8_t, bfg[nt]),
                                acc[mt][nt], 0, 0, 0);
                    __builtin_amdgcn_s_setprio(0);
                }
            }
        }
        __syncthreads();                 // all waves done with buf; stage(p+1) landed
        if (p + 2 < 8) stage(buf, p + 2);    // refill freed slot, overlaps phase p+1
    }

    // ---- epilogue (R6 scattered-store form): demod, noise, bias, lrelu, gain,
    //      clamp; wave writes its 64 co x 64 px of row y = y0 + ri.
    //      32x32 C/D: col = lane&31, row = (reg&3) + 8*(reg>>2) + 4*hi ----
    float nstr = nstrp[0];
    int y = y0 + ri;
    const float* nrow = noise + y * RES + w0 + pbase;
    float nz[2];
    #pragma unroll
    for (int nt = 0; nt < 2; ++nt)
        nz[nt] = nrow[nt * 32 + l31] * nstr;

    float* orow = out + (size_t)b * COUT * RES * RES + y * RES + w0 + pbase;
    #pragma unroll
    for (int mt = 0; mt < 2; ++mt) {
        #pragma unroll
        for (int rg = 0; rg < 16; ++rg) {
            int co = ch * 64 + mt * 32 + (rg & 3) + 8 * (rg >> 2) + 4 * hi;
            float dc = s_dc[co], bi = s_bias[co];
            #pragma unroll
            for (int nt = 0; nt < 2; ++nt) {
                int px = nt * 32 + l31;
                float v = acc[mt][nt][rg] * dc + nz[nt] + bi;
                v = (v >= 0.f) ? v : 0.2f * v;
                v *= 1.4142135623730951f;        // sqrt(2) gain
                v = fminf(fmaxf(v, -256.f), 256.f);
                orow[(size_t)co * RES * RES + px] = v;
            }
        }
    }
}

// ---- fallback (fused, no xb) if workspace can't hold xb; wb3 layout ----
__global__ __launch_bounds__(256) void k_conv_fb(
    const float* __restrict__ x, const float* __restrict__ noise,
    const float* __restrict__ nstrp, const float* __restrict__ bias,
    const float* __restrict__ styles, const float* __restrict__ dcoef,
    const unsigned short* __restrict__ wb3, float* __restrict__ out) {

    __shared__ s8_t xs[16 * 136];
    __shared__ float s_sty[CIN], s_dc[COUT], s_bias[COUT];

    int blk = blockIdx.x;
    int b   = blk >> 9;
    int rem = blk & 511;
    int h0  = rem >> 1;
    int w0  = (rem & 1) << 7;

    int tid = threadIdx.x;
    if (tid < 128) {
        s_sty[tid] = styles[b * CIN + tid];
    } else {
        s_dc[tid - 128]   = dcoef[b * COUT + tid - 128];
        s_bias[tid - 128] = bias[tid - 128];
    }

    int lane = tid & 63, wave = tid >> 6;
    int mbase = (wave & 1) * 64;
    int nbase = (wave >> 1) * 64;
    int l15 = lane & 15, quad = lane >> 4;

    f4_t acc[4][4];
    for (int m = 0; m < 4; ++m)
        for (int n = 0; n < 4; ++n)
            acc[m][n] = (f4_t)0.f;

    for (int kh = 0; kh < 3; ++kh) {
        int r = h0 - 1 + kh;
        bool rowok = (r >= 0) && (r < RES);
        int rc = rowok ? r : 0;
        const float* xrow = x + ((size_t)b * CIN * RES + rc) * RES;

        __syncthreads();
        for (int it = 0; it < 9; ++it) {
            int g = it * 256 + tid;
            if (g < 16 * 136) {
                int cig = g / 136, col = g - cig * 136;
                int wcol = w0 - 4 + col;
                bool ok = rowok && (wcol >= 0) && (wcol < RES);
                s8_t v8;
                for (int j = 0; j < 8; ++j) {
                    int ci = cig * 8 + j;
                    float v = ok ? xrow[(size_t)ci * RES * RES + wcol] * s_sty[ci] : 0.f;
                    v8[j] = (short)f2bf(v);
                }
                xs[g] = v8;
            }
        }
        __syncthreads();

        for (int kw = 0; kw < 3; ++kw) {
            int kk = kh * 3 + kw;
            for (int ks = 0; ks < 4; ++ks) {
                s8_t af[4], bfg[4];
                for (int mt = 0; mt < 4; ++mt) {
                    int co = mbase + mt * 16 + l15;
                    // ci = ks*32 + quad*8 + j -> ks16 = 2ks + (quad>>1), off = (quad&1)*8
                    af[mt] = *(const s8_t*)(wb3
                        + ((kk * 8 + 2 * ks + (quad >> 1)) * COUT + co) * 16
                        + (quad & 1) * 8);
                }
                int cig = ks * 4 + quad;
                for (int nt = 0; nt < 4; ++nt) {
                    int col = nbase + nt * 16 + l15 + kw + 3;
                    bfg[nt] = xs[cig * 136 + col];
                }
                for (int mt = 0; mt < 4; ++mt)
                    for (int nt = 0; nt < 4; ++nt)
                        acc[mt][nt] = __builtin_amdgcn_mfma_f32_16x16x32_bf16(
                            __builtin_bit_cast(bf8_t, af[mt]),
                            __builtin_bit_cast(bf8_t, bfg[nt]),
                            acc[mt][nt], 0, 0, 0);
            }
        }
    }

    float nstr = nstrp[0];
    const float* nrow = noise + h0 * RES + w0;
    float nz[4];
    for (int nt = 0; nt < 4; ++nt)
        nz[nt] = nrow[nbase + nt * 16 + l15] * nstr;

    float* orow = out + (size_t)b * COUT * RES * RES + h0 * RES + w0;
    for (int mt = 0; mt < 4; ++mt) {
        for (int rg = 0; rg < 4; ++rg) {
            int co = mbase + mt * 16 + quad * 4 + rg;
            float dc = s_dc[co], bi = s_bias[co];
            for (int nt = 0; nt < 4; ++nt) {
                int px = nbase + nt * 16 + l15;
                float v = acc[mt][nt][rg] * dc + nz[nt] + bi;
                v = (v >= 0.f) ? v : 0.2f * v;
                v *= 1.4142135623730951f;
                v = fminf(fmaxf(v, -256.f), 256.f);
                orow[(size_t)co * RES * RES + px] = v;
            }
        }
    }
}

extern "C" void kernel_launch(void* const* d_in, const int* in_sizes, int n_in,
                              void* d_out, int out_size, void* d_ws, size_t ws_size,
                              hipStream_t stream) {
    const float* x     = (const float*)d_in[0];
    const float* w     = (const float*)d_in[1];
    const float* aw    = (const float*)d_in[2];
    const float* ab    = (const float*)d_in[3];
    const float* wt    = (const float*)d_in[4];
    const float* noise = (const float*)d_in[5];
    const float* nstr  = (const float*)d_in[6];
    const float* bias  = (const float*)d_in[7];
    // d_in[8] = noise_mode (reference adds const noise unconditionally)

    float* ws     = (float*)d_ws;
    float* styles = ws;                    // [8][128] f32
    float* dcoef  = ws + 1024;             // [8][128] f32
    float* w2     = ws + 2048;             // [128][128] f32
    unsigned short* wb3 = (unsigned short*)(ws + 2048 + 16384);  // [72][128][16] bf16
    const size_t xb_off   = 368640;        // bytes: 4K+4K+64K+288K
    const size_t xb_bytes = (size_t)8 * 16 * PROWS * PCOLS * 16;  // 139,493,376
    unsigned short* xb = (unsigned short*)((char*)d_ws + xb_off);
    float* out = (float*)d_out;

    hipLaunchKernelGGL(k_styles, dim3(4),  dim3(256), 0, stream, w, aw, ab, styles);
    hipLaunchKernelGGL(k_wprep,  dim3(64), dim3(256), 0, stream, wt, w2, wb3);
    hipLaunchKernelGGL(k_dcoef,  dim3(4),  dim3(256), 0, stream, w2, styles, dcoef);

    if (ws_size >= xb_off + xb_bytes) {
        hipLaunchKernelGGL(k_prep_x,  dim3(34056), dim3(256), 0, stream, x, styles, xb);
        hipLaunchKernelGGL(k_conv19,  dim3(2048),  dim3(512), 0, stream,
                           noise, nstr, bias, dcoef, wb3, xb, out);
    } else {
        hipLaunchKernelGGL(k_conv_fb, dim3(4096), dim3(256), 0, stream,
                           x, noise, nstr, bias, styles, dcoef, wb3, out);
    }
}

// Round 21
// 265.003 us; speedup vs baseline: 1.1490x; 1.1490x over previous
//
#include <hip/hip_runtime.h>
#include <math.h>

typedef __bf16 bf8_t __attribute__((ext_vector_type(8)));
typedef short  s8_t  __attribute__((ext_vector_type(8)));
typedef float  f4_t  __attribute__((ext_vector_type(4)));

#define CIN   128
#define COUT  128
#define RES   256
#define WDIM  512
#define PROWS 258   // padded rows: -1 .. 256
#define PCOLS 264   // padded cols: -4 .. 259
#define PSTR  135   // LDS plane stride in 16B groups
#define BGRP  (8 * PSTR)   // 1080 groups per half-row buffer

// round-to-nearest-even f32 -> bf16 bits (inputs finite, no NaN handling)
static __device__ __forceinline__ unsigned short f2bf(float f) {
    unsigned u = __float_as_uint(f);
    unsigned r = (u + 0x7fffu + ((u >> 16) & 1u)) >> 16;
    return (unsigned short)r;
}

// ---- prep 1: styles[b][i] = (w[b]·affine_w[i])/sqrt(512) + affine_b[i] ----
__global__ void k_styles(const float* __restrict__ w, const float* __restrict__ aw,
                         const float* __restrict__ ab, float* __restrict__ styles) {
    int t = blockIdx.x * 256 + threadIdx.x;      // 1024 threads: (b, i)
    int b = t >> 7, i = t & 127;
    const float4* wr = (const float4*)(w + b * WDIM);
    const float4* ar = (const float4*)(aw + i * WDIM);
    float s = 0.f;
    for (int j = 0; j < WDIM / 4; ++j) {
        float4 a = ar[j], c = wr[j];
        s += a.x * c.x + a.y * c.y + a.z * c.z + a.w * c.w;
    }
    styles[t] = s * 0.04419417382415922f + ab[i];   // 1/sqrt(512)
}

// ---- prep 2: w2[o][i] = sum_k weight^2 ;
//      wb2[((kk*4+ks)*128+o)*32 + ci32] = bf16(weight[o][ks*32+ci32][kk])
//      (coalesced-A layout: one MFMA A-fragment = permuted-contiguous 1KB) ----
__global__ void k_wprep(const float* __restrict__ wt, float* __restrict__ w2,
                        unsigned short* __restrict__ wb2) {
    int t = blockIdx.x * 256 + threadIdx.x;      // 16384 threads: (o, i)
    int o = t >> 7, i = t & 127;
    int ks = i >> 5, c5 = i & 31;
    float s = 0.f;
    for (int kk = 0; kk < 9; ++kk) {
        float v = wt[(o * CIN + i) * 9 + kk];
        s += v * v;
        wb2[((kk * 4 + ks) * COUT + o) * 32 + c5] = f2bf(v);
    }
    w2[o * CIN + i] = s;
}

// ---- prep 3: dcoef[b][o] = 1/sqrt(sum_i w2[o][i]*styles[b][i]^2 + 1e-8) ----
__global__ void k_dcoef(const float* __restrict__ w2, const float* __restrict__ styles,
                        float* __restrict__ dcoef) {
    int t = blockIdx.x * 256 + threadIdx.x;      // 1024 threads: (b, o)
    int b = t >> 7, o = t & 127;
    float s = 0.f;
    for (int i = 0; i < CIN; ++i) {
        float st = styles[b * CIN + i];
        s += w2[o * CIN + i] * st * st;
    }
    dcoef[t] = 1.0f / sqrtf(s + 1e-8f);
}

// ---- prep 4: modulated bf16 x in MFMA-native padded layout ----
// xb flat group index t = ((b*16+cig)*PROWS + pr)*PCOLS + pc ; group = 8 ch = 16B
// pr = row+1 (rows -1..256), pc = col+4 (cols -4..259); pads are zero.
__global__ __launch_bounds__(256) void k_prep_x(
    const float* __restrict__ x, const float* __restrict__ styles,
    unsigned short* __restrict__ xb) {
    int t = blockIdx.x * 256 + threadIdx.x;      // 8*16*258*264 = 8,718,336 groups
    int pc = t % PCOLS;
    int r1 = t / PCOLS;
    int pr = r1 % PROWS;
    int bc = r1 / PROWS;                         // b*16 + cig
    int b = bc >> 4, cig = bc & 15;
    int r = pr - 1, c = pc - 4;
    unsigned short v[8];
    if ((r >= 0) & (r < RES) & (c >= 0) & (c < RES)) {
        const float* xp = x + (((size_t)b * CIN + cig * 8) * RES + r) * RES + c;
        const float* st = styles + b * CIN + cig * 8;
        #pragma unroll
        for (int j = 0; j < 8; ++j)
            v[j] = f2bf(__builtin_nontemporal_load(xp + (size_t)j * RES * RES) * st[j]);
    } else {
        #pragma unroll
        for (int j = 0; j < 8; ++j) v[j] = 0;
    }
    *(s8_t*)(xb + (size_t)t * 8) = *(const s8_t*)v;   // 16B/lane, wave-contiguous
}

// ---- main: R17 champion (restored; R18 PSTR/batch and R20 32x32-MFMA both
//      regressed). 2 rows x 128 co x 128 px per block, 8 waves =
//      (co-quarter cq, row ri), mt=2 x nt=8, acc[2][8] = 64 AGPR. Per step
//      2 af L2-loads feed 16 MFMA; bfg in 2 batches of 4. 8 half-row phases,
//      2-slot gload_lds ring. R6 scattered epilogue (proven best). ----
__global__ __launch_bounds__(512, 4) void k_conv17(
    const float* __restrict__ noise, const float* __restrict__ nstrp,
    const float* __restrict__ bias, const float* __restrict__ dcoef,
    const unsigned short* __restrict__ wb2, const unsigned short* __restrict__ xb,
    float* __restrict__ out) {

    __shared__ s8_t xs[2][BGRP];                 // 2 x 17280 B ring
    __shared__ float s_dc[COUT], s_bias[COUT];   // 1 KB  (total 35.6 KB)

    int blk0 = blockIdx.x;
    int blk  = (blk0 & 7) * 256 + (blk0 >> 3);   // XCD swizzle (2048 blocks, bijective)
    int b   = blk >> 8;
    int rem = blk & 255;
    int y0  = (rem >> 1) << 1;                   // first output row (even)
    int w0  = (rem & 1) << 7;

    int tid = threadIdx.x;
    int lane = tid & 63, wave = tid >> 6;        // 8 waves
    int cq = wave & 3;                           // co-quarter (32 co)
    int ri = wave >> 2;                          // output-row offset 0/1
    int mbase = cq * 32;
    int l15 = lane & 15, quad = lane >> 4;

    const unsigned short* xbb = xb + (size_t)b * ((size_t)16 * PROWS * PCOLS * 8);
    // per-lane A base: lane offset l15*32 + quad*8 elems inside each 1KB fragment
    const unsigned short* awp = wb2 + (mbase + l15) * 32 + quad * 8;

    // stage phase p (padded row pr = y0 + p/2, ci-half = p&1) into ring slot:
    // 1080 groups, linear LDS dest, 17 wave-loads spread over 8 waves
    auto stage = [&](int slot, int p) {
        int pr = y0 + (p >> 1);
        int cb = (p & 1) * 8;
        #pragma unroll
        for (int li = 0; li < 3; ++li) {
            int l = wave + li * 8;               // l in 0..16
            if (l < 17) {
                int g = l * 64 + lane;
                if (g < BGRP) {
                    int cig = (int)(((unsigned)g * 31069u) >> 22);   // g / 135
                    int col = g - cig * PSTR;
                    int cs = col > 131 ? 131 : col;  // pad groups: dup col 131
                    const unsigned short* src = xbb
                        + (((size_t)(cb + cig) * PROWS + pr) * PCOLS + (w0 + 2 + cs)) * 8;
                    __builtin_amdgcn_global_load_lds(
                        (const __attribute__((address_space(1))) unsigned int*)src,
                        (__attribute__((address_space(3))) unsigned int*)&xs[slot][g],
                        16, 0, 0);
                }
            }
        }
    };

    f4_t acc[2][8];                              // [mt][nt] = 64 AGPR
    #pragma unroll
    for (int m = 0; m < 2; ++m)
        #pragma unroll
        for (int n = 0; n < 8; ++n)
            acc[m][n] = (f4_t)0.f;

    // prologue: fill both slots, then small table loads
    stage(0, 0);
    stage(1, 1);
    if (tid < 128)      s_dc[tid] = dcoef[b * COUT + tid];
    else if (tid < 256) s_bias[tid - 128] = bias[tid - 128];
    __syncthreads();                             // drains all prologue loads

    // 8 phases: row = p>>1 (pr = y0+row), half = p&1. Wave computes kh = row - ri.
    #pragma unroll
    for (int p = 0; p < 8; ++p) {
        int buf = p & 1;
        int row = p >> 1, half = p & 1;
        int kh = row - ri;
        if (kh >= 0 && kh <= 2) {                // wave-uniform branch
            #pragma unroll
            for (int kw = 0; kw < 3; ++kw) {
                int kk = kh * 3 + kw;
                #pragma unroll
                for (int ks2 = 0; ks2 < 2; ++ks2) {
                    int ks = half * 2 + ks2;
                    const unsigned short* ak = awp + (kk * 4 + ks) * COUT * 32;
                    s8_t af[2];
                    #pragma unroll
                    for (int mt = 0; mt < 2; ++mt)
                        af[mt] = *(const s8_t*)(ak + mt * 16 * 32);  // contiguous 1KB
                    #pragma unroll
                    for (int nb = 0; nb < 2; ++nb) {   // bfg batch of 4 (VGPR cap)
                        s8_t bfg[4];
                        #pragma unroll
                        for (int n4 = 0; n4 < 4; ++n4)
                            bfg[n4] = xs[buf][(ks2 * 4 + quad) * PSTR
                                              + (nb * 4 + n4) * 16 + l15 + kw + 1];
                        __builtin_amdgcn_s_setprio(1);
                        #pragma unroll
                        for (int mt = 0; mt < 2; ++mt)
                            #pragma unroll
                            for (int n4 = 0; n4 < 4; ++n4)
                                acc[mt][nb * 4 + n4] =
                                    __builtin_amdgcn_mfma_f32_16x16x32_bf16(
                                        __builtin_bit_cast(bf8_t, af[mt]),
                                        __builtin_bit_cast(bf8_t, bfg[n4]),
                                        acc[mt][nb * 4 + n4], 0, 0, 0);
                        __builtin_amdgcn_s_setprio(0);
                    }
                }
            }
        }
        __syncthreads();                 // all waves done with buf; stage(p+1) landed
        if (p + 2 < 8) stage(buf, p + 2);    // refill freed slot, overlaps phase p+1
    }

    // ---- epilogue (R6 scattered-store form, measured best): demod, noise,
    //      bias, lrelu, gain, clamp; wave writes its 32 co x 128 px of row y ----
    float nstr = nstrp[0];
    int y = y0 + ri;
    const float* nrow = noise + y * RES + w0;
    float nz[8];
    #pragma unroll
    for (int nt = 0; nt < 8; ++nt)
        nz[nt] = nrow[nt * 16 + l15] * nstr;

    float* orow = out + (size_t)b * COUT * RES * RES + y * RES + w0;
    #pragma unroll
    for (int mt = 0; mt < 2; ++mt) {
        #pragma unroll
        for (int rg = 0; rg < 4; ++rg) {
            int co = mbase + mt * 16 + quad * 4 + rg;   // C/D: row = quad*4+reg
            float dc = s_dc[co], bi = s_bias[co];
            #pragma unroll
            for (int nt = 0; nt < 8; ++nt) {
                int px = nt * 16 + l15;                  // C/D: col = lane&15
                float v = acc[mt][nt][rg] * dc + nz[nt] + bi;
                v = (v >= 0.f) ? v : 0.2f * v;
                v *= 1.4142135623730951f;                // sqrt(2) gain
                v = fminf(fmaxf(v, -256.f), 256.f);
                orow[(size_t)co * RES * RES + px] = v;
            }
        }
    }
}

// ---- fallback (fused, no xb) if workspace can't hold xb; uses wb2 layout ----
__global__ __launch_bounds__(256) void k_conv_fb(
    const float* __restrict__ x, const float* __restrict__ noise,
    const float* __restrict__ nstrp, const float* __restrict__ bias,
    const float* __restrict__ styles, const float* __restrict__ dcoef,
    const unsigned short* __restrict__ wb2, float* __restrict__ out) {

    __shared__ s8_t xs[16 * 136];
    __shared__ float s_sty[CIN], s_dc[COUT], s_bias[COUT];

    int blk = blockIdx.x;
    int b   = blk >> 9;
    int rem = blk & 511;
    int h0  = rem >> 1;
    int w0  = (rem & 1) << 7;

    int tid = threadIdx.x;
    if (tid < 128) {
        s_sty[tid] = styles[b * CIN + tid];
    } else {
        s_dc[tid - 128]   = dcoef[b * COUT + tid - 128];
        s_bias[tid - 128] = bias[tid - 128];
    }

    int lane = tid & 63, wave = tid >> 6;
    int mbase = (wave & 1) * 64;
    int nbase = (wave >> 1) * 64;
    int l15 = lane & 15, quad = lane >> 4;

    f4_t acc[4][4];
    for (int m = 0; m < 4; ++m)
        for (int n = 0; n < 4; ++n)
            acc[m][n] = (f4_t)0.f;

    for (int kh = 0; kh < 3; ++kh) {
        int r = h0 - 1 + kh;
        bool rowok = (r >= 0) && (r < RES);
        int rc = rowok ? r : 0;
        const float* xrow = x + ((size_t)b * CIN * RES + rc) * RES;

        __syncthreads();
        for (int it = 0; it < 9; ++it) {
            int g = it * 256 + tid;
            if (g < 16 * 136) {
                int cig = g / 136, col = g - cig * 136;
                int wcol = w0 - 4 + col;
                bool ok = rowok && (wcol >= 0) && (wcol < RES);
                s8_t v8;
                for (int j = 0; j < 8; ++j) {
                    int ci = cig * 8 + j;
                    float v = ok ? xrow[(size_t)ci * RES * RES + wcol] * s_sty[ci] : 0.f;
                    v8[j] = (short)f2bf(v);
                }
                xs[g] = v8;
            }
        }
        __syncthreads();

        for (int kw = 0; kw < 3; ++kw) {
            int kk = kh * 3 + kw;
            for (int ks = 0; ks < 4; ++ks) {
                s8_t af[4], bfg[4];
                for (int mt = 0; mt < 4; ++mt) {
                    int co = mbase + mt * 16 + l15;
                    af[mt] = *(const s8_t*)(wb2 + ((kk * 4 + ks) * COUT + co) * 32
                                            + quad * 8);
                }
                int cig = ks * 4 + quad;
                for (int nt = 0; nt < 4; ++nt) {
                    int col = nbase + nt * 16 + l15 + kw + 3;
                    bfg[nt] = xs[cig * 136 + col];
                }
                for (int mt = 0; mt < 4; ++mt)
                    for (int nt = 0; nt < 4; ++nt)
                        acc[mt][nt] = __builtin_amdgcn_mfma_f32_16x16x32_bf16(
                            __builtin_bit_cast(bf8_t, af[mt]),
                            __builtin_bit_cast(bf8_t, bfg[nt]),
                            acc[mt][nt], 0, 0, 0);
            }
        }
    }

    float nstr = nstrp[0];
    const float* nrow = noise + h0 * RES + w0;
    float nz[4];
    for (int nt = 0; nt < 4; ++nt)
        nz[nt] = nrow[nbase + nt * 16 + l15] * nstr;

    float* orow = out + (size_t)b * COUT * RES * RES + h0 * RES + w0;
    for (int mt = 0; mt < 4; ++mt) {
        for (int rg = 0; rg < 4; ++rg) {
            int co = mbase + mt * 16 + quad * 4 + rg;
            float dc = s_dc[co], bi = s_bias[co];
            for (int nt = 0; nt < 4; ++nt) {
                int px = nbase + nt * 16 + l15;
                float v = acc[mt][nt][rg] * dc + nz[nt] + bi;
                v = (v >= 0.f) ? v : 0.2f * v;
                v *= 1.4142135623730951f;
                v = fminf(fmaxf(v, -256.f), 256.f);
                orow[(size_t)co * RES * RES + px] = v;
            }
        }
    }
}

extern "C" void kernel_launch(void* const* d_in, const int* in_sizes, int n_in,
                              void* d_out, int out_size, void* d_ws, size_t ws_size,
                              hipStream_t stream) {
    const float* x     = (const float*)d_in[0];
    const float* w     = (const float*)d_in[1];
    const float* aw    = (const float*)d_in[2];
    const float* ab    = (const float*)d_in[3];
    const float* wt    = (const float*)d_in[4];
    const float* noise = (const float*)d_in[5];
    const float* nstr  = (const float*)d_in[6];
    const float* bias  = (const float*)d_in[7];
    // d_in[8] = noise_mode (reference adds const noise unconditionally)

    float* ws     = (float*)d_ws;
    float* styles = ws;                    // [8][128] f32
    float* dcoef  = ws + 1024;             // [8][128] f32
    float* w2     = ws + 2048;             // [128][128] f32
    unsigned short* wb2 = (unsigned short*)(ws + 2048 + 16384);  // [36][128][32] bf16
    const size_t xb_off   = 368640;        // bytes: 4K+4K+64K+288K
    const size_t xb_bytes = (size_t)8 * 16 * PROWS * PCOLS * 16;  // 139,493,376
    unsigned short* xb = (unsigned short*)((char*)d_ws + xb_off);
    float* out = (float*)d_out;

    hipLaunchKernelGGL(k_styles, dim3(4),  dim3(256), 0, stream, w, aw, ab, styles);
    hipLaunchKernelGGL(k_wprep,  dim3(64), dim3(256), 0, stream, wt, w2, wb2);
    hipLaunchKernelGGL(k_dcoef,  dim3(4),  dim3(256), 0, stream, w2, styles, dcoef);

    if (ws_size >= xb_off + xb_bytes) {
        hipLaunchKernelGGL(k_prep_x,  dim3(34056), dim3(256), 0, stream, x, styles, xb);
        hipLaunchKernelGGL(k_conv17,  dim3(2048),  dim3(512), 0, stream,
                           noise, nstr, bias, dcoef, wb2, xb, out);
    } else {
        hipLaunchKernelGGL(k_conv_fb, dim3(4096), dim3(256), 0, stream,
                           x, noise, nstr, bias, styles, dcoef, wb2, out);
    }
}